// Round 11
// baseline (461.807 us; speedup 1.0000x reference)
//
#include <hip/hip_runtime.h>
#include <math.h>

#define NTOT 4608          // N_IN * DIM * DIM
#define NCH  96            // chunks
#define NPC  48            // n per chunk
#define NPW  12            // n per wave (4 waves/block)

typedef _Float16 f16;
typedef _Float16 f16x4 __attribute__((ext_vector_type(4)));
typedef _Float16 f16x8 __attribute__((ext_vector_type(8)));
typedef float f32x4 __attribute__((ext_vector_type(4)));

// ---- prep: blockIdx < 2304 -> wt[n][j*16+o][d] f16 (LDS-staged transpose of W)
//            blockIdx >= 2304 -> ut[b][n][d] f16 <- x[b][d][n]
__global__ __launch_bounds__(320) void prep(const float* __restrict__ x, const float* __restrict__ W,
                                            f16* __restrict__ ut, f16* __restrict__ wt) {
    __shared__ float l[2560];
    const int k = threadIdx.x;           // 0..319
    if (blockIdx.x < 2304) {
        const int n0 = blockIdx.x * 2;
        #pragma unroll
        for (int r = 0; r < 8; ++r) {
            const int f = k + r * 320;
            const int p = f / 20, q = f - p * 20;
            l[f] = W[(size_t)p * 46080 + n0 * 10 + q];
        }
        __syncthreads();
        const int half = k / 160, rr = k - half * 160;    // rr = j*16 + o
        const int j = rr >> 4, o = rr & 15;
        f16x8 v;
        #pragma unroll
        for (int d = 0; d < 8; ++d)
            v[d] = (f16)l[d * 320 + o * 20 + half * 10 + j];
        *reinterpret_cast<f16x8*>(wt + ((size_t)(n0 + half) * 160 + rr) * 8) = v;
    } else {
        const int t = (blockIdx.x - 2304) * 320 + k;      // b*4608 + n
        if (t < 128 * NTOT) {
            const int b = t / NTOT, n = t - b * NTOT;
            f16x8 v;
            #pragma unroll
            for (int d = 0; d < 8; ++d)
                v[d] = (f16)x[((size_t)b * 8 + d) * NTOT + n];
            *reinterpret_cast<f16x8*>(ut + (size_t)t * 8) = v;
        }
    }
}

// ---- kernelA: materialize u_hat (f16, layout [n][sg=0..19][b][8 halves]) + iter-0 partials.
// grid (96, 8). Wave w: n = chunk*48 + w*12 .. +12, 16 b. K-dup MFMA -> C = 4*u_hat.
// Store f16x4(0.25*C). Partial carries 4x (RS sumscale 0.025 = 0.1 * 0.25).
__global__ __launch_bounds__(256) void kernelA(const f16* __restrict__ ut, const f16* __restrict__ wt,
                                               f16* __restrict__ uh, float* __restrict__ partial) {
    __shared__ float s0t[4][16][164];
    const int tid = threadIdx.x, w = tid >> 6, lane = tid & 63;
    const int col = lane & 15, qA = lane >> 4;
    const int chunk = blockIdx.x, bg = blockIdx.y, b0 = bg * 16;
    const int b = b0 + col;
    const int nstart = chunk * NPC + w * NPW;

    const f16* ab = wt + ((size_t)nstart * 160 + col) * 8;
    const f16* ub = ut + ((size_t)b * NTOT + nstart) * 8;
    f16* uhw = uh + (size_t)nstart * 20480 + (size_t)(qA >> 1) * 1024 + b * 8 + (qA & 1) * 4;

    const f32x4 cz = {0.f, 0.f, 0.f, 0.f};
    f32x4 s0a[10];
    #pragma unroll
    for (int m = 0; m < 10; ++m) s0a[m] = cz;

    for (int nl = 0; nl < NPW; ++nl) {
        const f16x8 bf = *reinterpret_cast<const f16x8*>(ub + nl * 8);
        #pragma unroll
        for (int m = 0; m < 10; ++m) {
            const f16x8 af = *reinterpret_cast<const f16x8*>(ab + ((size_t)nl * 160 + m * 16) * 8);
            f32x4 C = __builtin_amdgcn_mfma_f32_16x16x32_f16(af, bf, cz, 0, 0, 0);
            s0a[m] += C;
            f16x4 hv;
            hv[0] = (f16)(0.25f * C[0]); hv[1] = (f16)(0.25f * C[1]);
            hv[2] = (f16)(0.25f * C[2]); hv[3] = (f16)(0.25f * C[3]);
            *reinterpret_cast<f16x4*>(uhw + (size_t)nl * 20480 + m * 2048) = hv;
        }
    }

    #pragma unroll
    for (int m = 0; m < 10; ++m)
        *reinterpret_cast<f32x4*>(&s0t[w][col][m * 16 + qA * 4]) = s0a[m];
    __syncthreads();
    for (int r = tid; r < 2560; r += 256) {
        const int row = r / 160, slot = r - row * 160;
        float v = s0t[0][row][slot] + s0t[1][row][slot] + s0t[2][row][slot] + s0t[3][row][slot];
        partial[((size_t)chunk * 128 + b0 + row) * 160 + slot] = v;
    }
}

// ---- kernelB body: one routing iteration from materialized u_hat.
// __launch_bounds__(256,3): VGPR budget ~170 so Af[40]+P[40]+U[20] stay resident
// (no per-nl rematerialization/spill). No max-subtract: logits bounded |L|<~35.
__device__ __forceinline__ void kernelB_impl(const f16* __restrict__ uh, const float* __restrict__ Ar,
                                             float* __restrict__ partial, int chunk) {
    __shared__ float s1t[4][16][164];
    const int tid = threadIdx.x, w = tid >> 6, lane = tid & 63;
    const int g = lane & 15, q = lane >> 4;
    const int bg = blockIdx.y;
    const int b = bg * 16 + g;
    const int nstart = chunk * NPC + w * NPW;
    const bool qlow = (q < 2);

    float Af[5][8];
    #pragma unroll
    for (int s = 0; s < 5; ++s) {
        f32x4 a0 = *reinterpret_cast<const f32x4*>(Ar + (size_t)b * 160 + (4 * s + q) * 8);
        f32x4 a1 = *reinterpret_cast<const f32x4*>(Ar + (size_t)b * 160 + (4 * s + q) * 8 + 4);
        #pragma unroll
        for (int t = 0; t < 4; ++t) { Af[s][t] = a0[t]; Af[s][4 + t] = a1[t]; }
    }

    float P[5][8];
    #pragma unroll
    for (int s = 0; s < 5; ++s)
        #pragma unroll
        for (int t = 0; t < 8; ++t) P[s][t] = 0.f;

    const f16* uhb = uh + (size_t)nstart * 20480 + (size_t)q * 1024 + b * 8;

    #pragma unroll
    for (int nl = 0; nl < NPW; ++nl) {
        f16x8 U[5];
        #pragma unroll
        for (int s = 0; s < 5; ++s)
            U[s] = *reinterpret_cast<const f16x8*>(uhb + (size_t)nl * 20480 + s * 4096);

        float tp[5];
        #pragma unroll
        for (int s = 0; s < 5; ++s) {
            float acc = 0.f;
            #pragma unroll
            for (int t = 0; t < 8; ++t)
                acc = fmaf(Af[s][t], (float)U[s][t], acc);
            tp[s] = acc;
        }

        float tt[10];
        #pragma unroll
        for (int s = 0; s < 5; ++s) {
            float tq = tp[s] + __shfl_xor(tp[s], 16, 64);
            float tr = __shfl_xor(tq, 32, 64);
            tt[2 * s]     = qlow ? tq : tr;
            tt[2 * s + 1] = qlow ? tr : tq;
        }

        float c[10], sum = 0.f;
        #pragma unroll
        for (int j = 0; j < 10; ++j) { float e = __expf(tt[j]); c[j] = e; sum += e; }
        const float inv = 1.0f / sum;

        #pragma unroll
        for (int s = 0; s < 5; ++s) {
            const float cm = (qlow ? c[2 * s] : c[2 * s + 1]) * inv;
            #pragma unroll
            for (int t = 0; t < 8; ++t)
                P[s][t] = fmaf(cm, (float)U[s][t], P[s][t]);
        }
    }

    #pragma unroll
    for (int s = 0; s < 5; ++s) {
        const int S = (4 * s + q) * 8;
        f32x4 p0 = {P[s][0], P[s][1], P[s][2], P[s][3]};
        f32x4 p1 = {P[s][4], P[s][5], P[s][6], P[s][7]};
        *reinterpret_cast<f32x4*>(&s1t[w][g][S])     = p0;
        *reinterpret_cast<f32x4*>(&s1t[w][g][S + 4]) = p1;
    }
    __syncthreads();
    for (int r = tid; r < 2560; r += 256) {
        const int row = r / 160, slot = r - row * 160;
        float v = s1t[0][row][slot] + s1t[1][row][slot] + s1t[2][row][slot] + s1t[3][row][slot];
        partial[((size_t)chunk * 128 + bg * 16 + row) * 160 + slot] = v;
    }
}

// DESC=true walks chunks high->low (L3 tail reuse right after kernelA); B2 ascending.
template<bool DESC>
__global__ __launch_bounds__(256, 3) void kernelB(const f16* __restrict__ uh,
                                                  const float* __restrict__ Ar,
                                                  float* __restrict__ partial) {
    const int chunk = DESC ? (NCH - 1 - (int)blockIdx.x) : (int)blockIdx.x;
    kernelB_impl(uh, Ar, partial, chunk);
}

// ---- reduce_squash: sum 96 chunk-partials, squash, update A-state / write out.
// grid (128 b, 2 j-halves) x 320 threads; k2 = j'*16+o, r = chunk-stripe 0..3.
template<int MODE>   // 0: Ar = s   1: Ar += s   2: out = s
__global__ __launch_bounds__(320) void reduce_squash(const float* __restrict__ partial,
                                                     float* __restrict__ Ar, float* __restrict__ out,
                                                     float sumscale) {
    const int b = blockIdx.x, jh = blockIdx.y;
    const int k2 = threadIdx.x % 80;
    const int r  = threadIdx.x / 80;     // 0..3
    const int jp = k2 >> 4, o = k2 & 15;
    const int j  = jh * 5 + jp;
    const int slot = j * 16 + o;
    __shared__ float red[4][80];
    __shared__ float srs[80];
    float acc = 0.f;
    for (int c = r; c < NCH; c += 4)
        acc += partial[((size_t)c * 128 + b) * 160 + slot];
    red[r][k2] = acc;
    __syncthreads();
    if (r == 0) srs[k2] = (red[0][k2] + red[1][k2] + red[2][k2] + red[3][k2]) * sumscale;
    __syncthreads();
    if (r == 0) {
        float ssq = 0.f;
        #pragma unroll
        for (int oo = 0; oo < 16; ++oo) { float v = srs[jp * 16 + oo]; ssq = fmaf(v, v, ssq); }
        const float s = srs[k2] * ssq / ((1.f + ssq) * sqrtf(ssq));
        if (MODE == 0)      Ar[(size_t)b * 160 + slot] = s;
        else if (MODE == 1) Ar[(size_t)b * 160 + slot] += s;
        else                out[(size_t)b * 160 + o * 10 + j] = s;
    }
}

extern "C" void kernel_launch(void* const* d_in, const int* in_sizes, int n_in,
                              void* d_out, int out_size, void* d_ws, size_t ws_size,
                              hipStream_t stream) {
    const float* x = (const float*)d_in[0];   // (128, 8, 32, 12, 12)
    const float* W = (const float*)d_in[1];   // (8, 16, 4608, 10)
    float* out = (float*)d_out;               // (128, 16, 10)

    f16* ut = (f16*)d_ws;                                   // 128*4608*8 h     = 9.4 MB
    f16* wt = ut + (size_t)128 * NTOT * 8;                  // 4608*160*8 h     = 11.8 MB
    f16* uh = wt + (size_t)NTOT * 160 * 8;                  // 4608*20*128*8 h  = 188.7 MB
    float* Ar = (float*)(uh + (size_t)NTOT * 20 * 128 * 8); // 128*160 f32
    float* partial = Ar + 128 * 160;                        // 96*128*160 f32   = 7.9 MB

    prep<<<2304 + 1844, 320, 0, stream>>>(x, W, ut, wt);

    dim3 gA(NCH, 8), gRS(128, 2);
    kernelA<<<gA, 256, 0, stream>>>(ut, wt, uh, partial);
    reduce_squash<0><<<gRS, 320, 0, stream>>>(partial, Ar, out, 0.025f);  // 0.1 (c0) * 0.25 (K-dup)

    kernelB<true ><<<gA, 256, 0, stream>>>(uh, Ar, partial);
    reduce_squash<1><<<gRS, 320, 0, stream>>>(partial, Ar, out, 1.0f);

    kernelB<false><<<gA, 256, 0, stream>>>(uh, Ar, partial);
    reduce_squash<2><<<gRS, 320, 0, stream>>>(partial, Ar, out, 1.0f);
}

// Round 12
// 172.347 us; speedup vs baseline: 2.6795x; 2.6795x over previous
//
#include <hip/hip_runtime.h>
#include <math.h>

#define NTOT 4608          // N_IN * DIM * DIM
#define NCH  144           // chunks
#define NPC  32            // n per chunk
#define NPW  8             // n per wave (4 waves/block)

typedef _Float16 f16;
typedef _Float16 f16x4 __attribute__((ext_vector_type(4)));
typedef _Float16 f16x8 __attribute__((ext_vector_type(8)));
typedef float f32x4 __attribute__((ext_vector_type(4)));

// ---- prep: blockIdx < 2304 -> wt[n][j*16+o][d] f16 (LDS-staged transpose of W)
//            blockIdx >= 2304 -> ut[b][n][d] f16 <- x[b][d][n]
__global__ __launch_bounds__(320) void prep(const float* __restrict__ x, const float* __restrict__ W,
                                            f16* __restrict__ ut, f16* __restrict__ wt) {
    __shared__ float l[2560];
    const int k = threadIdx.x;           // 0..319
    if (blockIdx.x < 2304) {
        const int n0 = blockIdx.x * 2;
        #pragma unroll
        for (int r = 0; r < 8; ++r) {
            const int f = k + r * 320;
            const int p = f / 20, q = f - p * 20;
            l[f] = W[(size_t)p * 46080 + n0 * 10 + q];
        }
        __syncthreads();
        const int half = k / 160, rr = k - half * 160;    // rr = j*16 + o
        const int j = rr >> 4, o = rr & 15;
        f16x8 v;
        #pragma unroll
        for (int d = 0; d < 8; ++d)
            v[d] = (f16)l[d * 320 + o * 20 + half * 10 + j];
        *reinterpret_cast<f16x8*>(wt + ((size_t)(n0 + half) * 160 + rr) * 8) = v;
    } else {
        const int t = (blockIdx.x - 2304) * 320 + k;      // b*4608 + n
        if (t < 128 * NTOT) {
            const int b = t / NTOT, n = t - b * NTOT;
            f16x8 v;
            #pragma unroll
            for (int d = 0; d < 8; ++d)
                v[d] = (f16)x[((size_t)b * 8 + d) * NTOT + n];
            *reinterpret_cast<f16x8*>(ut + (size_t)t * 8) = v;
        }
    }
}

// ---- kernelA: materialize u_hat (f16, layout [n][sg=0..19][b][8 halves]) + iter-0 partials.
// grid (144, 8). Wave w: n = chunk*32 + w*8 .. +8, 16 b. K-dup MFMA -> C = 4*u_hat.
// Store f16x4(0.25*C). Partial carries 4x (RS sumscale 0.025 = 0.1 * 0.25).
// Epilogue: single 16x164 LDS buffer, barrier-ordered cross-wave accumulation (10.5 KB).
__global__ __launch_bounds__(256) void kernelA(const f16* __restrict__ ut, const f16* __restrict__ wt,
                                               f16* __restrict__ uh, float* __restrict__ partial) {
    __shared__ float s0t[16][164];
    const int tid = threadIdx.x, w = tid >> 6, lane = tid & 63;
    const int col = lane & 15, qA = lane >> 4;
    const int chunk = blockIdx.x, bg = blockIdx.y, b0 = bg * 16;
    const int b = b0 + col;
    const int nstart = chunk * NPC + w * NPW;

    const f16* ab = wt + ((size_t)nstart * 160 + col) * 8;
    const f16* ub = ut + ((size_t)b * NTOT + nstart) * 8;
    f16* uhw = uh + (size_t)nstart * 20480 + (size_t)(qA >> 1) * 1024 + b * 8 + (qA & 1) * 4;

    const f32x4 cz = {0.f, 0.f, 0.f, 0.f};
    f32x4 s0a[10];
    #pragma unroll
    for (int m = 0; m < 10; ++m) s0a[m] = cz;

    for (int nl = 0; nl < NPW; ++nl) {
        const f16x8 bf = *reinterpret_cast<const f16x8*>(ub + nl * 8);
        #pragma unroll
        for (int m = 0; m < 10; ++m) {
            const f16x8 af = *reinterpret_cast<const f16x8*>(ab + ((size_t)nl * 160 + m * 16) * 8);
            f32x4 C = __builtin_amdgcn_mfma_f32_16x16x32_f16(af, bf, cz, 0, 0, 0);
            s0a[m] += C;
            f16x4 hv;
            hv[0] = (f16)(0.25f * C[0]); hv[1] = (f16)(0.25f * C[1]);
            hv[2] = (f16)(0.25f * C[2]); hv[3] = (f16)(0.25f * C[3]);
            *reinterpret_cast<f16x4*>(uhw + (size_t)nl * 20480 + m * 2048) = hv;
        }
    }

    // ordered cross-wave accumulate into the single LDS tile (deterministic)
    for (int ww = 0; ww < 4; ++ww) {
        if (w == ww) {
            if (ww == 0) {
                #pragma unroll
                for (int m = 0; m < 10; ++m)
                    *reinterpret_cast<f32x4*>(&s0t[col][m * 16 + qA * 4]) = s0a[m];
            } else {
                #pragma unroll
                for (int m = 0; m < 10; ++m) {
                    f32x4 old = *reinterpret_cast<f32x4*>(&s0t[col][m * 16 + qA * 4]);
                    old += s0a[m];
                    *reinterpret_cast<f32x4*>(&s0t[col][m * 16 + qA * 4]) = old;
                }
            }
        }
        __syncthreads();
    }
    for (int r = tid; r < 2560; r += 256) {
        const int row = r / 160, slot = r - row * 160;
        partial[((size_t)chunk * 128 + b0 + row) * 160 + slot] = s0t[row][slot];
    }
}

// ---- kernelB body: one routing iteration from materialized u_hat.
// Same compute as the 166-us round-7 kernel; only the epilogue LDS changed
// (16x164 single buffer + ordered adds) so occupancy moves from 3 to ~6 blocks/CU.
__device__ __forceinline__ void kernelB_impl(const f16* __restrict__ uh, const float* __restrict__ Ar,
                                             float* __restrict__ partial, int chunk) {
    __shared__ float s1t[16][164];
    const int tid = threadIdx.x, w = tid >> 6, lane = tid & 63;
    const int g = lane & 15, q = lane >> 4;
    const int bg = blockIdx.y;
    const int b = bg * 16 + g;
    const int nstart = chunk * NPC + w * NPW;
    const bool qlow = (q < 2);

    float Af[5][8];
    #pragma unroll
    for (int s = 0; s < 5; ++s) {
        f32x4 a0 = *reinterpret_cast<const f32x4*>(Ar + (size_t)b * 160 + (4 * s + q) * 8);
        f32x4 a1 = *reinterpret_cast<const f32x4*>(Ar + (size_t)b * 160 + (4 * s + q) * 8 + 4);
        #pragma unroll
        for (int t = 0; t < 4; ++t) { Af[s][t] = a0[t]; Af[s][4 + t] = a1[t]; }
    }

    float P[5][8];
    #pragma unroll
    for (int s = 0; s < 5; ++s)
        #pragma unroll
        for (int t = 0; t < 8; ++t) P[s][t] = 0.f;

    const f16* uhb = uh + (size_t)nstart * 20480 + (size_t)q * 1024 + b * 8;

    for (int nl = 0; nl < NPW; ++nl) {
        f16x8 U[5];
        #pragma unroll
        for (int s = 0; s < 5; ++s)
            U[s] = *reinterpret_cast<const f16x8*>(uhb + (size_t)nl * 20480 + s * 4096);

        float tp[5];
        #pragma unroll
        for (int s = 0; s < 5; ++s) {
            float acc = 0.f;
            #pragma unroll
            for (int t = 0; t < 8; ++t)
                acc = fmaf(Af[s][t], (float)U[s][t], acc);
            tp[s] = acc;
        }

        float tt[10];
        #pragma unroll
        for (int s = 0; s < 5; ++s) {
            float tq = tp[s] + __shfl_xor(tp[s], 16, 64);
            float tr = __shfl_xor(tq, 32, 64);
            tt[2 * s]     = qlow ? tq : tr;
            tt[2 * s + 1] = qlow ? tr : tq;
        }

        float mx = fmaxf(fmaxf(fmaxf(fmaxf(tt[0], tt[1]), fmaxf(tt[2], tt[3])),
                               fmaxf(fmaxf(tt[4], tt[5]), fmaxf(tt[6], tt[7]))),
                         fmaxf(tt[8], tt[9]));
        float c[10], sum = 0.f;
        #pragma unroll
        for (int j = 0; j < 10; ++j) { float e = __expf(tt[j] - mx); c[j] = e; sum += e; }
        const float inv = 1.0f / sum;

        #pragma unroll
        for (int s = 0; s < 5; ++s) {
            const float cm = (qlow ? c[2 * s] : c[2 * s + 1]) * inv;
            #pragma unroll
            for (int t = 0; t < 8; ++t)
                P[s][t] = fmaf(cm, (float)U[s][t], P[s][t]);
        }
    }

    for (int ww = 0; ww < 4; ++ww) {
        if (w == ww) {
            if (ww == 0) {
                #pragma unroll
                for (int s = 0; s < 5; ++s) {
                    const int S = (4 * s + q) * 8;
                    f32x4 p0 = {P[s][0], P[s][1], P[s][2], P[s][3]};
                    f32x4 p1 = {P[s][4], P[s][5], P[s][6], P[s][7]};
                    *reinterpret_cast<f32x4*>(&s1t[g][S])     = p0;
                    *reinterpret_cast<f32x4*>(&s1t[g][S + 4]) = p1;
                }
            } else {
                #pragma unroll
                for (int s = 0; s < 5; ++s) {
                    const int S = (4 * s + q) * 8;
                    f32x4 o0 = *reinterpret_cast<f32x4*>(&s1t[g][S]);
                    f32x4 o1 = *reinterpret_cast<f32x4*>(&s1t[g][S + 4]);
                    o0[0] += P[s][0]; o0[1] += P[s][1]; o0[2] += P[s][2]; o0[3] += P[s][3];
                    o1[0] += P[s][4]; o1[1] += P[s][5]; o1[2] += P[s][6]; o1[3] += P[s][7];
                    *reinterpret_cast<f32x4*>(&s1t[g][S])     = o0;
                    *reinterpret_cast<f32x4*>(&s1t[g][S + 4]) = o1;
                }
            }
        }
        __syncthreads();
    }
    for (int r = tid; r < 2560; r += 256) {
        const int row = r / 160, slot = r - row * 160;
        partial[((size_t)chunk * 128 + bg * 16 + row) * 160 + slot] = s1t[row][slot];
    }
}

// DESC=true walks chunks high->low (L3 tail reuse right after kernelA); B2 ascending.
template<bool DESC>
__global__ __launch_bounds__(256) void kernelB(const f16* __restrict__ uh,
                                               const float* __restrict__ Ar,
                                               float* __restrict__ partial) {
    const int chunk = DESC ? (NCH - 1 - (int)blockIdx.x) : (int)blockIdx.x;
    kernelB_impl(uh, Ar, partial, chunk);
}

// ---- reduce_squash: sum 144 chunk-partials, squash, update A-state / write out.
// grid (128 b, 2 j-halves) x 320 threads; k2 = j'*16+o, r = chunk-stripe 0..3.
template<int MODE>   // 0: Ar = s   1: Ar += s   2: out = s
__global__ __launch_bounds__(320) void reduce_squash(const float* __restrict__ partial,
                                                     float* __restrict__ Ar, float* __restrict__ out,
                                                     float sumscale) {
    const int b = blockIdx.x, jh = blockIdx.y;
    const int k2 = threadIdx.x % 80;
    const int r  = threadIdx.x / 80;     // 0..3
    const int jp = k2 >> 4, o = k2 & 15;
    const int j  = jh * 5 + jp;
    const int slot = j * 16 + o;
    __shared__ float red[4][80];
    __shared__ float srs[80];
    float acc = 0.f;
    for (int c = r; c < NCH; c += 4)
        acc += partial[((size_t)c * 128 + b) * 160 + slot];
    red[r][k2] = acc;
    __syncthreads();
    if (r == 0) srs[k2] = (red[0][k2] + red[1][k2] + red[2][k2] + red[3][k2]) * sumscale;
    __syncthreads();
    if (r == 0) {
        float ssq = 0.f;
        #pragma unroll
        for (int oo = 0; oo < 16; ++oo) { float v = srs[jp * 16 + oo]; ssq = fmaf(v, v, ssq); }
        const float s = srs[k2] * ssq / ((1.f + ssq) * sqrtf(ssq));
        if (MODE == 0)      Ar[(size_t)b * 160 + slot] = s;
        else if (MODE == 1) Ar[(size_t)b * 160 + slot] += s;
        else                out[(size_t)b * 160 + o * 10 + j] = s;
    }
}

extern "C" void kernel_launch(void* const* d_in, const int* in_sizes, int n_in,
                              void* d_out, int out_size, void* d_ws, size_t ws_size,
                              hipStream_t stream) {
    const float* x = (const float*)d_in[0];   // (128, 8, 32, 12, 12)
    const float* W = (const float*)d_in[1];   // (8, 16, 4608, 10)
    float* out = (float*)d_out;               // (128, 16, 10)

    f16* ut = (f16*)d_ws;                                   // 128*4608*8 h     = 9.4 MB
    f16* wt = ut + (size_t)128 * NTOT * 8;                  // 4608*160*8 h     = 11.8 MB
    f16* uh = wt + (size_t)NTOT * 160 * 8;                  // 4608*20*128*8 h  = 188.7 MB
    float* Ar = (float*)(uh + (size_t)NTOT * 20 * 128 * 8); // 128*160 f32
    float* partial = Ar + 128 * 160;                        // 144*128*160 f32  = 11.8 MB

    prep<<<2304 + 1844, 320, 0, stream>>>(x, W, ut, wt);

    dim3 gA(NCH, 8), gRS(128, 2);
    kernelA<<<gA, 256, 0, stream>>>(ut, wt, uh, partial);
    reduce_squash<0><<<gRS, 320, 0, stream>>>(partial, Ar, out, 0.025f);  // 0.1 (c0) * 0.25 (K-dup)

    kernelB<true ><<<gA, 256, 0, stream>>>(uh, Ar, partial);
    reduce_squash<1><<<gRS, 320, 0, stream>>>(partial, Ar, out, 1.0f);

    kernelB<false><<<gA, 256, 0, stream>>>(uh, Ar, partial);
    reduce_squash<2><<<gRS, 320, 0, stream>>>(partial, Ar, out, 1.0f);
}